// Round 1
// baseline (343.976 us; speedup 1.0000x reference)
//
#include <hip/hip_runtime.h>
#include <hip/hip_bf16.h>

// Problem constants (fixed by setup_inputs): B=64, T=1024, C=768, CK=64, R=256
#define BB 64
#define TT 1024
#define CC 768
#define CKK 64
#define SS 512   // T/2
#define RR 256
#define TOUT 768 // R + S

// ---------------------------------------------------------------------------
// Kernel 1: per (batch, even-row s) compute max_d dot(k[2s], k[2d+1]) and argmax.
// Grid: 64 batches x 8 s-blocks = 512 blocks, 256 threads (64 rows x 4 quarters).
// B-rows staged in LDS tiles of 128 rows, row stride 68 floats (pad 4) so the
// 4 quarter-lanes hit disjoint banks; reads broadcast to 16 lanes each.
// ---------------------------------------------------------------------------
__global__ __launch_bounds__(256) void score_kernel(
    const float* __restrict__ k, float* __restrict__ node_max,
    int* __restrict__ node_idx) {
  const int b = blockIdx.x >> 3;
  const int sb = blockIdx.x & 7;
  const int t = threadIdx.x;
  const int rloc = t >> 2;   // 0..63
  const int q = t & 3;       // d-quarter (interleaved stride-4)
  const int sr = sb * 64 + rloc;

  __shared__ float lds[128 * 68];

  // a-row (even token 2*sr) into registers: 16 float4 = 64 VGPRs
  float4 a4[16];
  const float4* arow = (const float4*)(k + ((size_t)b * TT + 2 * sr) * CKK);
#pragma unroll
  for (int c = 0; c < 16; ++c) a4[c] = arow[c];

  float mx = -3.4e38f;
  int mi = 0;

  for (int tile = 0; tile < 4; ++tile) {
    __syncthreads();
    // stage 128 odd-token rows: 2048 float4, 8 per thread, coalesced
#pragma unroll
    for (int l = 0; l < 8; ++l) {
      int f = t + l * 256;
      int row = f >> 4, c4 = f & 15;
      float4 v = ((const float4*)(k + ((size_t)b * TT + 2 * (tile * 128 + row) + 1) * CKK))[c4];
      *(float4*)(&lds[row * 68 + c4 * 4]) = v;
    }
    __syncthreads();

    for (int dd = 0; dd < 32; ++dd) {
      int dl = dd * 4 + q;  // ascending d within this thread
      const float4* brow = (const float4*)(&lds[dl * 68]);
      float4 acc = {0.f, 0.f, 0.f, 0.f};
#pragma unroll
      for (int c = 0; c < 16; ++c) {
        float4 bv = brow[c];
        acc.x += a4[c].x * bv.x;
        acc.y += a4[c].y * bv.y;
        acc.z += a4[c].z * bv.z;
        acc.w += a4[c].w * bv.w;
      }
      float dot = (acc.x + acc.y) + (acc.z + acc.w);
      int d = tile * 128 + dl;
      if (dot > mx) { mx = dot; mi = d; }  // strict > keeps first max (asc d)
    }
  }

  // combine 4 quarter-lanes; tie -> smaller d (argmax first-occurrence)
#pragma unroll
  for (int off = 1; off < 4; off <<= 1) {
    float ov = __shfl_xor(mx, off);
    int oi = __shfl_xor(mi, off);
    if (ov > mx || (ov == mx && oi < mi)) { mx = ov; mi = oi; }
  }

  if (q == 0) {
    if (sr == 0) { mx = -1e30f; mi = 0; }  // scores[:,0,:] = NEG_INF
    node_max[b * SS + sr] = mx;
    node_idx[b * SS + sr] = mi;
  }
}

// ---------------------------------------------------------------------------
// Kernel 2: per-batch stable descending argsort of node_max via bitonic sort
// on 64-bit keys: (~order_mapped(value) << 32) | index.  Ascending key sort ==
// descending value, ties broken by ascending index (jnp stable argsort).
// Writes unm_idx (positions R..S-1), src_idx (0..R-1), dst_idx = node_idx[src].
// ---------------------------------------------------------------------------
__global__ __launch_bounds__(512) void sort_kernel(
    const float* __restrict__ node_max, const int* __restrict__ node_idx,
    int* __restrict__ unm_idx, int* __restrict__ src_idx,
    int* __restrict__ dst_idx) {
  const int b = blockIdx.x;
  const int i = threadIdx.x;
  __shared__ unsigned long long key[SS];

  float v = node_max[b * SS + i];
  unsigned int u = __float_as_uint(v);
  unsigned int mapped = (u & 0x80000000u) ? ~u : (u | 0x80000000u);
  key[i] = ((unsigned long long)(~mapped) << 32) | (unsigned int)i;

  for (int kk = 2; kk <= SS; kk <<= 1) {
    for (int j = kk >> 1; j > 0; j >>= 1) {
      __syncthreads();
      int ixj = i ^ j;
      if (ixj > i) {
        unsigned long long A = key[i], Bv = key[ixj];
        bool up = ((i & kk) == 0);
        if ((A > Bv) == up) { key[i] = Bv; key[ixj] = A; }
      }
    }
  }
  __syncthreads();

  int e = (int)(key[i] & 0xffffffffu);
  if (i < RR) {
    src_idx[b * RR + i] = e;
    dst_idx[b * RR + i] = node_idx[b * SS + e];
  } else {
    unm_idx[b * RR + (i - RR)] = e;
  }
}

// ---------------------------------------------------------------------------
// Kernel 3a: write the full output fresh each call.
//  rows [0,R):   out[b][p]      = x[b][2*unm_idx[p]]      (gather copy)
//  rows [R,768): out[b][R+d]    = x[b][2*d+1]             (strided copy)
// One 768-float row per 192-thread block, float4 coalesced.
// ---------------------------------------------------------------------------
__global__ __launch_bounds__(192) void gather_kernel(
    const float* __restrict__ x, const int* __restrict__ unm_idx,
    float* __restrict__ out) {
  const int p = blockIdx.x % TOUT;
  const int b = blockIdx.x / TOUT;
  const int t = threadIdx.x;
  int srow = (p < RR) ? (2 * unm_idx[b * RR + p]) : (2 * (p - RR) + 1);
  const float4* src = (const float4*)(x + ((size_t)b * TT + srow) * CC);
  float4* dst = (float4*)(out + ((size_t)b * TOUT + p) * CC);
  dst[t] = src[t];
}

// ---------------------------------------------------------------------------
// Kernel 3b: scatter-add merged src rows into dst region.
//  out[b][R + dst_idx[i]] += x[b][2*src_idx[i]]   via HW fp32 atomics.
// ---------------------------------------------------------------------------
__global__ __launch_bounds__(192) void scatter_kernel(
    const float* __restrict__ x, const int* __restrict__ src_idx,
    const int* __restrict__ dst_idx, float* __restrict__ out) {
  const int i = blockIdx.x % RR;
  const int b = blockIdx.x / RR;
  const int t = threadIdx.x;
  int e = src_idx[b * RR + i];
  int d = dst_idx[b * RR + i];
  const float4 v = ((const float4*)(x + ((size_t)b * TT + 2 * e) * CC))[t];
  float* dst = out + ((size_t)b * TOUT + RR + d) * CC + t * 4;
  unsafeAtomicAdd(&dst[0], v.x);
  unsafeAtomicAdd(&dst[1], v.y);
  unsafeAtomicAdd(&dst[2], v.z);
  unsafeAtomicAdd(&dst[3], v.w);
}

extern "C" void kernel_launch(void* const* d_in, const int* in_sizes, int n_in,
                              void* d_out, int out_size, void* d_ws, size_t ws_size,
                              hipStream_t stream) {
  const float* x = (const float*)d_in[0];
  const float* k = (const float*)d_in[1];
  // d_in[2] is r (=256), fixed by the problem; hardcoded as RR.
  float* out = (float*)d_out;

  char* ws = (char*)d_ws;
  float* node_max = (float*)(ws + 0);        // 64*512*4   = 131072 B
  int* node_idx   = (int*)(ws + 131072);     // 131072 B
  int* unm_idx    = (int*)(ws + 262144);     // 64*256*4   = 65536 B
  int* src_idx    = (int*)(ws + 327680);     // 65536 B
  int* dst_idx    = (int*)(ws + 393216);     // 65536 B

  score_kernel<<<BB * 8, 256, 0, stream>>>(k, node_max, node_idx);
  sort_kernel<<<BB, SS, 0, stream>>>(node_max, node_idx, unm_idx, src_idx, dst_idx);
  gather_kernel<<<BB * TOUT, 192, 0, stream>>>(x, unm_idx, out);
  scatter_kernel<<<BB * RR, 192, 0, stream>>>(x, src_idx, dst_idx, out);
}

// Round 2
// 122.931 us; speedup vs baseline: 2.7981x; 2.7981x over previous
//
#include <hip/hip_runtime.h>
#include <hip/hip_bf16.h>

// Problem constants (fixed by setup_inputs): B=64, T=1024, C=768, CK=64, R=256
#define BB 64
#define TT 1024
#define CC 768
#define CKK 64
#define SS 512   // T/2
#define RR 256
#define TOUT 768 // R + S
#define ASTRIDE 68  // 64 + 4 pad: 16B-aligned, stride mod 32 = 4 -> 2-way max

// ---------------------------------------------------------------------------
// Kernel 1: register-tiled max-GEMM. scores[s,d] = dot(k[2s], k[2d+1]).
// Grid: 64 batches x 4 row-tiles x 4 col-tiles = 1024 blocks, 256 threads.
// Each block: 128x128 output tile; thread (tx,ty) owns rows ty+16i, cols
// tx+16j (i,j in 0..7). A reads broadcast (addr dep. on ty only); B reads are
// 2-way (free). Per 4-k step: 16 ds_read_b128 vs 256 FMA -> VALU-bound.
// Row (max, argmax-first) kept as packed u64: (mapped<<32)|(511-d), reduced
// via LDS atomicMax then one global atomicMax per row per block.
// ---------------------------------------------------------------------------
__global__ __launch_bounds__(256) void score_kernel(
    const float* __restrict__ k, unsigned long long* __restrict__ nodekey) {
  const int b  = blockIdx.x >> 4;
  const int rt = (blockIdx.x >> 2) & 3;
  const int ct = blockIdx.x & 3;
  const int t  = threadIdx.x;
  const int tx = t & 15, ty = t >> 4;

  __shared__ float As[128 * ASTRIDE];
  __shared__ float Bs[128 * ASTRIDE];
  __shared__ unsigned long long rowkey[128];

  // stage A (even tokens of row-tile) and B (odd tokens of col-tile)
#pragma unroll
  for (int l = 0; l < 8; ++l) {
    int f = t + l * 256;
    int row = f >> 4, c4 = f & 15;
    float4 va = ((const float4*)(k + ((size_t)b * TT + 2 * (rt * 128 + row)) * CKK))[c4];
    float4 vb = ((const float4*)(k + ((size_t)b * TT + 2 * (ct * 128 + row) + 1) * CKK))[c4];
    *(float4*)(&As[row * ASTRIDE + c4 * 4]) = va;
    *(float4*)(&Bs[row * ASTRIDE + c4 * 4]) = vb;
  }
  if (t < 128) rowkey[t] = 0ull;
  __syncthreads();

  float acc[8][8];
#pragma unroll
  for (int i = 0; i < 8; ++i)
#pragma unroll
    for (int j = 0; j < 8; ++j) acc[i][j] = 0.f;

  for (int k4 = 0; k4 < 16; ++k4) {
    float4 av[8], bv[8];
#pragma unroll
    for (int i = 0; i < 8; ++i)
      av[i] = *(const float4*)(&As[(ty + 16 * i) * ASTRIDE + k4 * 4]);
#pragma unroll
    for (int j = 0; j < 8; ++j)
      bv[j] = *(const float4*)(&Bs[(tx + 16 * j) * ASTRIDE + k4 * 4]);
#pragma unroll
    for (int i = 0; i < 8; ++i)
#pragma unroll
      for (int j = 0; j < 8; ++j) {
        acc[i][j] += av[i].x * bv[j].x;
        acc[i][j] += av[i].y * bv[j].y;
        acc[i][j] += av[i].z * bv[j].z;
        acc[i][j] += av[i].w * bv[j].w;
      }
  }

  // per-thread row-max over its 8 cols (cols ascend with j: strict > keeps
  // smallest d on ties), then packed-key atomicMax reduction
#pragma unroll
  for (int i = 0; i < 8; ++i) {
    float mx = acc[i][0];
    int mj = 0;
#pragma unroll
    for (int j = 1; j < 8; ++j)
      if (acc[i][j] > mx) { mx = acc[i][j]; mj = j; }
    int d = ct * 128 + tx + 16 * mj;
    unsigned int u = __float_as_uint(mx);
    unsigned int mapped = (u & 0x80000000u) ? ~u : (u | 0x80000000u);
    unsigned long long key =
        ((unsigned long long)mapped << 32) | (unsigned int)(SS - 1 - d);
    atomicMax(&rowkey[ty + 16 * i], key);
  }
  __syncthreads();
  if (t < 128) atomicMax(&nodekey[b * SS + rt * 128 + t], rowkey[t]);
}

// ---------------------------------------------------------------------------
// Kernel 2: per-batch stable descending argsort (bitonic, 64-bit keys) +
// build per-dst linked lists (head/nxt) inverting the src->dst scatter.
// ---------------------------------------------------------------------------
__global__ __launch_bounds__(512) void sort_kernel(
    const unsigned long long* __restrict__ nodekey,
    int* __restrict__ unm_idx, int* __restrict__ src_idx,
    int* __restrict__ head, int* __restrict__ nxt) {
  const int b = blockIdx.x;
  const int i = threadIdx.x;
  __shared__ unsigned long long key[SS];
  __shared__ int nodeidx[SS];
  __shared__ int headS[SS];
  __shared__ int nxtS[RR];

  unsigned long long nk = nodekey[b * SS + i];
  unsigned int mapped;
  int nidx;
  if (i == 0) {  // scores[:,0,:] forced to NEG_INF -> max=-1e30, argmax=0
    mapped = ~__float_as_uint(-1e30f);
    nidx = 0;
  } else {
    mapped = (unsigned int)(nk >> 32);
    nidx = SS - 1 - (int)(nk & 0xffffffffu);
  }
  nodeidx[i] = nidx;
  key[i] = ((unsigned long long)(~mapped) << 32) | (unsigned int)i;
  headS[i] = -1;

  for (int kk = 2; kk <= SS; kk <<= 1) {
    for (int j = kk >> 1; j > 0; j >>= 1) {
      __syncthreads();
      int ixj = i ^ j;
      if (ixj > i) {
        unsigned long long A = key[i], Bv = key[ixj];
        bool up = ((i & kk) == 0);
        if ((A > Bv) == up) { key[i] = Bv; key[ixj] = A; }
      }
    }
  }
  __syncthreads();

  int e = (int)(key[i] & 0xffffffffu);
  if (i < RR) {
    src_idx[b * RR + i] = e;
    int d = nodeidx[e];
    nxtS[i] = atomicExch(&headS[d], i);
  } else {
    unm_idx[b * RR + (i - RR)] = e;
  }
  __syncthreads();
  head[b * SS + i] = headS[i];
  if (i < RR) nxt[b * RR + i] = nxtS[i];
}

// ---------------------------------------------------------------------------
// Kernel 3: fused output assembly, one 768-float row per 192-thread block.
//  rows [0,R):   out = x[2*unm_idx[p]]
//  rows [R,768): out = x[2*d+1] + sum over chain of x[2*src_idx[i]]
// No atomics; fully coalesced float4.
// ---------------------------------------------------------------------------
__global__ __launch_bounds__(192) void gather_kernel(
    const float* __restrict__ x, const int* __restrict__ unm_idx,
    const int* __restrict__ src_idx, const int* __restrict__ head,
    const int* __restrict__ nxt, float* __restrict__ out) {
  const int p = blockIdx.x % TOUT;
  const int b = blockIdx.x / TOUT;
  const int t = threadIdx.x;
  float4* dst = (float4*)(out + ((size_t)b * TOUT + p) * CC);

  if (p < RR) {
    int srow = 2 * unm_idx[b * RR + p];
    dst[t] = ((const float4*)(x + ((size_t)b * TT + srow) * CC))[t];
  } else {
    int d = p - RR;
    float4 acc = ((const float4*)(x + ((size_t)b * TT + 2 * d + 1) * CC))[t];
    for (int i = head[b * SS + d]; i >= 0; i = nxt[b * RR + i]) {
      int e = src_idx[b * RR + i];
      float4 v = ((const float4*)(x + ((size_t)b * TT + 2 * e) * CC))[t];
      acc.x += v.x; acc.y += v.y; acc.z += v.z; acc.w += v.w;
    }
    dst[t] = acc;
  }
}

extern "C" void kernel_launch(void* const* d_in, const int* in_sizes, int n_in,
                              void* d_out, int out_size, void* d_ws, size_t ws_size,
                              hipStream_t stream) {
  const float* x = (const float*)d_in[0];
  const float* k = (const float*)d_in[1];
  float* out = (float*)d_out;

  char* ws = (char*)d_ws;
  unsigned long long* nodekey = (unsigned long long*)(ws);  // 64*512*8 = 262144
  int* unm_idx = (int*)(ws + 262144);                       // 64*256*4 =  65536
  int* src_idx = (int*)(ws + 327680);                       //             65536
  int* head    = (int*)(ws + 393216);                       // 64*512*4 = 131072
  int* nxt     = (int*)(ws + 524288);                       //             65536
                                                            // total 589824 B

  hipMemsetAsync(nodekey, 0, (size_t)BB * SS * 8, stream);
  score_kernel<<<BB * 16, 256, 0, stream>>>(k, nodekey);
  sort_kernel<<<BB, SS, 0, stream>>>(nodekey, unm_idx, src_idx, head, nxt);
  gather_kernel<<<BB * TOUT, 192, 0, stream>>>(x, unm_idx, src_idx, head, nxt, out);
}

// Round 3
// 119.496 us; speedup vs baseline: 2.8786x; 1.0287x over previous
//
#include <hip/hip_runtime.h>
#include <hip/hip_bf16.h>

// Problem constants (fixed by setup_inputs): B=64, T=1024, C=768, CK=64, R=256
#define BB 64
#define TT 1024
#define CC 768
#define CKK 64
#define SS 512   // T/2
#define RR 256
#define TOUT 768 // R + S
#define ASTRIDE 68  // 64 + 4 pad: 16B-aligned, stride mod 32 = 4 -> 2-way max

// ---------------------------------------------------------------------------
// Kernel 1: register-tiled max-GEMM. scores[s,d] = dot(k[2s], k[2d+1]).
// Grid: 64 batches x 4 row-tiles = 256 blocks, 256 threads. Each block owns a
// 128-row strip and loops over the 4 col-tiles of 128. Thread (tx,ty) owns
// rows ty+16i, cols ct*128 + tx+16j (i,j in 0..7). Per-row (max, argmax-first)
// kept as 8 packed u64 registers: (mapped_val<<32)|(511-d); cross-ct max in
// register, cross-tx max via 4 shfl_xor steps; lane tx==0 writes nodekey.
// No global atomics, no memset.
// ---------------------------------------------------------------------------
__global__ __launch_bounds__(256) void score_kernel(
    const float* __restrict__ k, unsigned long long* __restrict__ nodekey) {
  const int b  = blockIdx.x >> 2;
  const int rt = blockIdx.x & 3;
  const int t  = threadIdx.x;
  const int tx = t & 15, ty = t >> 4;

  __shared__ float As[128 * ASTRIDE];
  __shared__ float Bs[128 * ASTRIDE];

  // stage A strip (even tokens) once
#pragma unroll
  for (int l = 0; l < 8; ++l) {
    int f = t + l * 256;
    int row = f >> 4, c4 = f & 15;
    float4 va = ((const float4*)(k + ((size_t)b * TT + 2 * (rt * 128 + row)) * CKK))[c4];
    *(float4*)(&As[row * ASTRIDE + c4 * 4]) = va;
  }

  unsigned long long rkey[8];
#pragma unroll
  for (int i = 0; i < 8; ++i) rkey[i] = 0ull;

  for (int ct = 0; ct < 4; ++ct) {
    __syncthreads();  // previous compute done (and A staged, first iter)
#pragma unroll
    for (int l = 0; l < 8; ++l) {
      int f = t + l * 256;
      int row = f >> 4, c4 = f & 15;
      float4 vb = ((const float4*)(k + ((size_t)b * TT + 2 * (ct * 128 + row) + 1) * CKK))[c4];
      *(float4*)(&Bs[row * ASTRIDE + c4 * 4]) = vb;
    }
    __syncthreads();

    float acc[8][8];
#pragma unroll
    for (int i = 0; i < 8; ++i)
#pragma unroll
      for (int j = 0; j < 8; ++j) acc[i][j] = 0.f;

    for (int k4 = 0; k4 < 16; ++k4) {
      float4 av[8], bv[8];
#pragma unroll
      for (int i = 0; i < 8; ++i)
        av[i] = *(const float4*)(&As[(ty + 16 * i) * ASTRIDE + k4 * 4]);
#pragma unroll
      for (int j = 0; j < 8; ++j)
        bv[j] = *(const float4*)(&Bs[(tx + 16 * j) * ASTRIDE + k4 * 4]);
#pragma unroll
      for (int i = 0; i < 8; ++i)
#pragma unroll
        for (int j = 0; j < 8; ++j) {
          acc[i][j] += av[i].x * bv[j].x;
          acc[i][j] += av[i].y * bv[j].y;
          acc[i][j] += av[i].z * bv[j].z;
          acc[i][j] += av[i].w * bv[j].w;
        }
    }

    // fold this col-tile into the per-row running keys
#pragma unroll
    for (int i = 0; i < 8; ++i) {
      float mx = acc[i][0];
      int mj = 0;
#pragma unroll
      for (int j = 1; j < 8; ++j)
        if (acc[i][j] > mx) { mx = acc[i][j]; mj = j; }  // asc d: > keeps min d
      int d = ct * 128 + tx + 16 * mj;
      unsigned int u = __float_as_uint(mx);
      unsigned int mapped = (u & 0x80000000u) ? ~u : (u | 0x80000000u);
      unsigned long long key =
          ((unsigned long long)mapped << 32) | (unsigned int)(SS - 1 - d);
      if (key > rkey[i]) rkey[i] = key;
    }
  }

  // reduce across the 16 col-lanes (same ty -> 16 consecutive lanes in wave)
#pragma unroll
  for (int i = 0; i < 8; ++i) {
#pragma unroll
    for (int off = 1; off < 16; off <<= 1) {
      unsigned long long o = __shfl_xor(rkey[i], off);
      if (o > rkey[i]) rkey[i] = o;
    }
  }
  if (tx == 0) {
#pragma unroll
    for (int i = 0; i < 8; ++i)
      nodekey[b * SS + rt * 128 + ty + 16 * i] = rkey[i];
  }
}

// ---------------------------------------------------------------------------
// Kernel 2: per-batch stable descending argsort via hybrid bitonic sort on
// 64-bit keys (~mapped<<32 | index): stages with j<=32 are intra-wave
// shfl_xor (no barrier), only j>=64 goes through LDS (6 stages).
// Then build per-dst linked lists (head/nxt) inverting the src->dst scatter.
// ---------------------------------------------------------------------------
__global__ __launch_bounds__(512) void sort_kernel(
    const unsigned long long* __restrict__ nodekey,
    int* __restrict__ unm_idx, int* __restrict__ src_idx,
    int* __restrict__ head, int* __restrict__ nxt) {
  const int b = blockIdx.x;
  const int i = threadIdx.x;
  __shared__ unsigned long long key[SS];
  __shared__ int nodeidx[SS];
  __shared__ int headS[SS];
  __shared__ int nxtS[RR];

  unsigned long long nk = nodekey[b * SS + i];
  unsigned int mapped;
  int nidx;
  if (i == 0) {  // scores[:,0,:] forced to NEG_INF -> max=-1e30, argmax=0
    mapped = ~__float_as_uint(-1e30f);
    nidx = 0;
  } else {
    mapped = (unsigned int)(nk >> 32);
    nidx = SS - 1 - (int)(nk & 0xffffffffu);
  }
  nodeidx[i] = nidx;
  headS[i] = -1;
  unsigned long long my = ((unsigned long long)(~mapped) << 32) | (unsigned int)i;

  for (int kk = 2; kk <= SS; kk <<= 1) {
    for (int j = kk >> 1; j > 0; j >>= 1) {
      bool up = ((i & kk) == 0);
      bool lower = ((i & j) == 0);
      bool takeMin = (up == lower);
      unsigned long long partner;
      if (j >= 64) {
        key[i] = my;
        __syncthreads();
        partner = key[i ^ j];
        __syncthreads();
      } else {
        partner = __shfl_xor(my, j);
      }
      bool pSmaller = partner < my;
      my = (takeMin == pSmaller) ? partner : my;
    }
  }
  key[i] = my;
  __syncthreads();

  int e = (int)(my & 0xffffffffu);
  if (i < RR) {
    src_idx[b * RR + i] = e;
    int d = nodeidx[e];
    nxtS[i] = atomicExch(&headS[d], i);
  } else {
    unm_idx[b * RR + (i - RR)] = e;
  }
  __syncthreads();
  head[b * SS + i] = headS[i];
  if (i < RR) nxt[b * RR + i] = nxtS[i];
}

// ---------------------------------------------------------------------------
// Kernel 3: fused output assembly, one 768-float row per 192-thread block.
//  rows [0,R):   out = x[2*unm_idx[p]]
//  rows [R,768): out = x[2*d+1] + sum over chain of x[2*src_idx[i]]
// No atomics; fully coalesced float4.
// ---------------------------------------------------------------------------
__global__ __launch_bounds__(192) void gather_kernel(
    const float* __restrict__ x, const int* __restrict__ unm_idx,
    const int* __restrict__ src_idx, const int* __restrict__ head,
    const int* __restrict__ nxt, float* __restrict__ out) {
  const int p = blockIdx.x % TOUT;
  const int b = blockIdx.x / TOUT;
  const int t = threadIdx.x;
  float4* dst = (float4*)(out + ((size_t)b * TOUT + p) * CC);

  if (p < RR) {
    int srow = 2 * unm_idx[b * RR + p];
    dst[t] = ((const float4*)(x + ((size_t)b * TT + srow) * CC))[t];
  } else {
    int d = p - RR;
    float4 acc = ((const float4*)(x + ((size_t)b * TT + 2 * d + 1) * CC))[t];
    for (int i = head[b * SS + d]; i >= 0; i = nxt[b * RR + i]) {
      int e = src_idx[b * RR + i];
      float4 v = ((const float4*)(x + ((size_t)b * TT + 2 * e) * CC))[t];
      acc.x += v.x; acc.y += v.y; acc.z += v.z; acc.w += v.w;
    }
    dst[t] = acc;
  }
}

extern "C" void kernel_launch(void* const* d_in, const int* in_sizes, int n_in,
                              void* d_out, int out_size, void* d_ws, size_t ws_size,
                              hipStream_t stream) {
  const float* x = (const float*)d_in[0];
  const float* k = (const float*)d_in[1];
  float* out = (float*)d_out;

  char* ws = (char*)d_ws;
  unsigned long long* nodekey = (unsigned long long*)(ws);  // 64*512*8 = 262144
  int* unm_idx = (int*)(ws + 262144);                       // 64*256*4 =  65536
  int* src_idx = (int*)(ws + 327680);                       //             65536
  int* head    = (int*)(ws + 393216);                       // 64*512*4 = 131072
  int* nxt     = (int*)(ws + 524288);                       //             65536
                                                            // total 589824 B

  score_kernel<<<BB * 4, 256, 0, stream>>>(k, nodekey);
  sort_kernel<<<BB, SS, 0, stream>>>(nodekey, unm_idx, src_idx, head, nxt);
  gather_kernel<<<BB * TOUT, 192, 0, stream>>>(x, unm_idx, src_idx, head, nxt, out);
}